// Round 2
// baseline (2442.696 us; speedup 1.0000x reference)
//
#include <hip/hip_runtime.h>
#include <math.h>

#define NN 20000
#define H 256
#define R 64
#define EE 320000
#define LN_EPS 1e-5f

__device__ __forceinline__ float silu_f(float x) { return x / (1.0f + __expf(-x)); }

// ---------------------------------------------------------------------------
// K1: fused LayerNorm + Q/K/V projections.  16 nodes per 256-thread block.
// ---------------------------------------------------------------------------
__global__ __launch_bounds__(256) void k_ln_qkv(
    const float* __restrict__ x, const float* __restrict__ g, const float* __restrict__ b,
    const float* __restrict__ Wq, const float* __restrict__ bq,
    const float* __restrict__ Wk, const float* __restrict__ bk,
    const float* __restrict__ Wv, const float* __restrict__ bv,
    float* __restrict__ q, float* __restrict__ k, float* __restrict__ v)
{
    __shared__ float xn[16][H];          // 16 KB
    const int t  = threadIdx.x;
    const int n0 = blockIdx.x * 16;

    #pragma unroll
    for (int i = 0; i < 16; ++i) xn[i][t] = x[(size_t)(n0 + i) * H + t];
    __syncthreads();

    const int n = t >> 4, s = t & 15;
    float sum = 0.f, sq = 0.f;
    #pragma unroll
    for (int j = 0; j < 16; ++j) { float val = xn[n][s + 16 * j]; sum += val; sq += val * val; }
    #pragma unroll
    for (int off = 8; off; off >>= 1) { sum += __shfl_xor(sum, off); sq += __shfl_xor(sq, off); }
    const float mu  = sum * (1.0f / H);
    const float var = sq * (1.0f / H) - mu * mu;
    const float rs  = rsqrtf(var + LN_EPS);
    #pragma unroll
    for (int j = 0; j < 16; ++j) {
        int c = s + 16 * j;
        float val = xn[n][c];
        xn[n][c] = (val - mu) * rs * g[c] + b[c];
    }
    __syncthreads();

    float aq[16], ak[16], av[16];
    #pragma unroll
    for (int i = 0; i < 16; ++i) { aq[i] = 0.f; ak[i] = 0.f; av[i] = 0.f; }
    const float* wqr = Wq + (size_t)t * H;
    const float* wkr = Wk + (size_t)t * H;
    const float* wvr = Wv + (size_t)t * H;
    for (int kk = 0; kk < H; kk += 4) {
        const float4 wq4 = *(const float4*)(wqr + kk);
        const float4 wk4 = *(const float4*)(wkr + kk);
        const float4 wv4 = *(const float4*)(wvr + kk);
        #pragma unroll
        for (int i = 0; i < 16; ++i) {
            const float4 x4 = *(const float4*)&xn[i][kk];
            aq[i] += wq4.x * x4.x + wq4.y * x4.y + wq4.z * x4.z + wq4.w * x4.w;
            ak[i] += wk4.x * x4.x + wk4.y * x4.y + wk4.z * x4.z + wk4.w * x4.w;
            av[i] += wv4.x * x4.x + wv4.y * x4.y + wv4.z * x4.z + wv4.w * x4.w;
        }
    }
    const float bqv = bq[t], bkv = bk[t], bvv = bv[t];
    #pragma unroll
    for (int i = 0; i < 16; ++i) {
        q[(size_t)(n0 + i) * H + t] = aq[i] + bqv;
        k[(size_t)(n0 + i) * H + t] = ak[i] + bkv;
        v[(size_t)(n0 + i) * H + t] = av[i] + bvv;
    }
}

// ---------------------------------------------------------------------------
// Counting sort of edges by dst: hist -> scan -> scatter(perm)
// ---------------------------------------------------------------------------
__global__ __launch_bounds__(256) void k_hist(const int* __restrict__ ei, int* __restrict__ hist) {
    int e = blockIdx.x * 256 + threadIdx.x;
    if (e < EE) atomicAdd(&hist[ei[EE + e]], 1);
}

__global__ __launch_bounds__(1024) void k_scan(const int* __restrict__ hist,
                                               int* __restrict__ off, int* __restrict__ cursor) {
    __shared__ int buf[1024];
    __shared__ int carry_s;
    const int t = threadIdx.x;
    if (t == 0) carry_s = 0;
    __syncthreads();
    for (int base = 0; base < NN; base += 1024) {
        int vv = (base + t < NN) ? hist[base + t] : 0;
        buf[t] = vv;
        __syncthreads();
        #pragma unroll
        for (int ofs = 1; ofs < 1024; ofs <<= 1) {
            int add = (t >= ofs) ? buf[t - ofs] : 0;
            __syncthreads();
            buf[t] += add;
            __syncthreads();
        }
        int excl = buf[t] - vv;
        int carry = carry_s;
        if (base + t < NN) { int o = carry + excl; off[base + t] = o; cursor[base + t] = o; }
        __syncthreads();
        if (t == 1023) carry_s = carry + buf[1023];
        __syncthreads();
    }
    if (t == 0) off[NN] = carry_s;
}

__global__ __launch_bounds__(256) void k_scatter(const int* __restrict__ ei,
                                                 int* __restrict__ cursor, int* __restrict__ perm) {
    int e = blockIdx.x * 256 + threadIdx.x;
    if (e < EE) {
        int d = ei[EE + e];
        int pos = atomicAdd(&cursor[d], 1);
        perm[pos] = e;
    }
}

// ---------------------------------------------------------------------------
// K2: segmented edge kernel. Block b owns nodes [16b,16b+16) and ALL their
// edges (sorted by dst). Aggregation in LDS (ds atomics), single coalesced
// global store per agg row. No global atomics, no memset.
// GEMM micro-kernel: h-quarters (64 cols), per-thread tile 4 edges x 4 cols.
// ---------------------------------------------------------------------------
__global__ __launch_bounds__(256) void k_edge_seg(
    const float* __restrict__ q, const float* __restrict__ k, const float* __restrict__ v,
    const int* __restrict__ ei, const float* __restrict__ ew, const float* __restrict__ ea,
    const float* __restrict__ Wdk, const float* __restrict__ bdk,
    const float* __restrict__ Wdv, const float* __restrict__ bdv,
    const int* __restrict__ off, const int* __restrict__ perm,
    float* __restrict__ agg)
{
    __shared__ float agg_s[16][H];    // 16 KB
    __shared__ float w_s[R][64];      // 16 KB (one h-quarter, transposed)
    __shared__ float ea_s[64][R];     // 16 KB
    __shared__ float attn_s[64], cut_s[64];
    __shared__ int   pe_s[64], src_s[64], dst_s[64], nrel_s[64];

    const int t  = threadIdx.x;
    const int n0 = blockIdx.x * 16;

    #pragma unroll
    for (int i = 0; i < 4; ++i)
        ((float4*)agg_s)[t + 256 * i] = float4{0.f, 0.f, 0.f, 0.f};

    const int e_start = off[n0];
    const int e_end   = off[n0 + 16];

    const int tx = t & 15, ty = t >> 4;     // 16 col-threads x 16 edge-groups
    const int h0 = tx * 4, e0l = ty * 4;    // 4 cols, 4 edges per thread

    for (int chunk = e_start; chunk < e_end; chunk += 64) {
        const int ne = min(64, e_end - chunk);
        __syncthreads();   // prior chunk's readers of ea_s/meta done
        if (t < 64) {
            const int i = t;
            const bool valid = i < ne;
            int e = valid ? perm[chunk + i] : -1;
            int s = n0, d = n0; float r = 1e9f;
            if (valid) { s = ei[e]; d = ei[EE + e]; r = ew[e]; }
            pe_s[i] = e; src_s[i] = s; dst_s[i] = d; nrel_s[i] = d - n0;
            cut_s[i] = (r < 5.0f) ? 0.5f * (__cosf(r * 0.6283185307f) + 1.0f) : 0.0f;
            attn_s[i] = 0.f;
        }
        __syncthreads();   // pe_s visible
        {   // stage ea rows: 4 threads per row, 4 float4 each
            const int row = t >> 2, c0 = (t & 3) * 16;
            const int e = pe_s[row];
            if (e >= 0) {
                const float* sp = ea + (size_t)e * R + c0;
                #pragma unroll
                for (int j = 0; j < 4; ++j)
                    *(float4*)&ea_s[row][c0 + 4 * j] = *(const float4*)(sp + 4 * j);
            } else {
                #pragma unroll
                for (int j = 0; j < 4; ++j)
                    *(float4*)&ea_s[row][c0 + 4 * j] = float4{0.f, 0.f, 0.f, 0.f};
            }
        }

        // ---------------- pass A: attention logits ----------------
        for (int hq = 0; hq < 4; ++hq) {
            __syncthreads();   // ea_s ready / prior w_s readers done
            {   // w_s[r][hl] = Wdk[(hq*64+hl)*R + r]
                const int hl = t & 63, r0 = (t >> 6) * 16;
                const float* wp = Wdk + (size_t)(hq * 64 + hl) * R + r0;
                #pragma unroll
                for (int j4 = 0; j4 < 16; j4 += 4) {
                    const float4 w4 = *(const float4*)(wp + j4);
                    w_s[r0 + j4 + 0][hl] = w4.x;
                    w_s[r0 + j4 + 1][hl] = w4.y;
                    w_s[r0 + j4 + 2][hl] = w4.z;
                    w_s[r0 + j4 + 3][hl] = w4.w;
                }
            }
            __syncthreads();

            float4 acc[4];
            const float4 bi = *(const float4*)(bdk + hq * 64 + h0);
            #pragma unroll
            for (int i = 0; i < 4; ++i) acc[i] = bi;

            for (int r4 = 0; r4 < R; r4 += 4) {
                const float4 w0 = *(const float4*)&w_s[r4 + 0][h0];
                const float4 w1 = *(const float4*)&w_s[r4 + 1][h0];
                const float4 w2 = *(const float4*)&w_s[r4 + 2][h0];
                const float4 w3 = *(const float4*)&w_s[r4 + 3][h0];
                #pragma unroll
                for (int i = 0; i < 4; ++i) {
                    const float4 a = *(const float4*)&ea_s[e0l + i][r4];
                    acc[i].x += a.x * w0.x + a.y * w1.x + a.z * w2.x + a.w * w3.x;
                    acc[i].y += a.x * w0.y + a.y * w1.y + a.z * w2.y + a.w * w3.y;
                    acc[i].z += a.x * w0.z + a.y * w1.z + a.z * w2.z + a.w * w3.z;
                    acc[i].w += a.x * w0.w + a.y * w1.w + a.z * w2.w + a.w * w3.w;
                }
            }
            #pragma unroll
            for (int i = 0; i < 4; ++i) {
                const int d = dst_s[e0l + i], s = src_s[e0l + i];
                const float4 qi = *(const float4*)(q + (size_t)d * H + hq * 64 + h0);
                const float4 kj = *(const float4*)(k + (size_t)s * H + hq * 64 + h0);
                float part = qi.x * kj.x * silu_f(acc[i].x) + qi.y * kj.y * silu_f(acc[i].y)
                           + qi.z * kj.z * silu_f(acc[i].z) + qi.w * kj.w * silu_f(acc[i].w);
                #pragma unroll
                for (int o = 8; o; o >>= 1) part += __shfl_xor(part, o);
                if (tx == 0) attn_s[e0l + i] += part;
            }
        }
        __syncthreads();
        if (t < 64) attn_s[t] = silu_f(attn_s[t]) * cut_s[t];

        // ---------------- pass B: messages + LDS scatter ----------------
        for (int hq = 0; hq < 4; ++hq) {
            __syncthreads();
            {
                const int hl = t & 63, r0 = (t >> 6) * 16;
                const float* wp = Wdv + (size_t)(hq * 64 + hl) * R + r0;
                #pragma unroll
                for (int j4 = 0; j4 < 16; j4 += 4) {
                    const float4 w4 = *(const float4*)(wp + j4);
                    w_s[r0 + j4 + 0][hl] = w4.x;
                    w_s[r0 + j4 + 1][hl] = w4.y;
                    w_s[r0 + j4 + 2][hl] = w4.z;
                    w_s[r0 + j4 + 3][hl] = w4.w;
                }
            }
            __syncthreads();

            float4 acc[4];
            const float4 bi = *(const float4*)(bdv + hq * 64 + h0);
            #pragma unroll
            for (int i = 0; i < 4; ++i) acc[i] = bi;

            for (int r4 = 0; r4 < R; r4 += 4) {
                const float4 w0 = *(const float4*)&w_s[r4 + 0][h0];
                const float4 w1 = *(const float4*)&w_s[r4 + 1][h0];
                const float4 w2 = *(const float4*)&w_s[r4 + 2][h0];
                const float4 w3 = *(const float4*)&w_s[r4 + 3][h0];
                #pragma unroll
                for (int i = 0; i < 4; ++i) {
                    const float4 a = *(const float4*)&ea_s[e0l + i][r4];
                    acc[i].x += a.x * w0.x + a.y * w1.x + a.z * w2.x + a.w * w3.x;
                    acc[i].y += a.x * w0.y + a.y * w1.y + a.z * w2.y + a.w * w3.y;
                    acc[i].z += a.x * w0.z + a.y * w1.z + a.z * w2.z + a.w * w3.z;
                    acc[i].w += a.x * w0.w + a.y * w1.w + a.z * w2.w + a.w * w3.w;
                }
            }
            #pragma unroll
            for (int i = 0; i < 4; ++i) {
                const int s = src_s[e0l + i], nr = nrel_s[e0l + i];
                const float a = attn_s[e0l + i];
                const float4 vj = *(const float4*)(v + (size_t)s * H + hq * 64 + h0);
                float* dp = &agg_s[nr][hq * 64 + h0];
                atomicAdd(dp + 0, vj.x * silu_f(acc[i].x) * a);
                atomicAdd(dp + 1, vj.y * silu_f(acc[i].y) * a);
                atomicAdd(dp + 2, vj.z * silu_f(acc[i].z) * a);
                atomicAdd(dp + 3, vj.w * silu_f(acc[i].w) * a);
            }
        }
    }

    __syncthreads();
    #pragma unroll
    for (int i = 0; i < 16; ++i)
        agg[(size_t)(n0 + i) * H + t] = agg_s[i][t];
}

// ---------------------------------------------------------------------------
// K3: out = x + agg @ Wo^T + bo.
// ---------------------------------------------------------------------------
__global__ __launch_bounds__(256) void k_out(
    const float* __restrict__ aggm, const float* __restrict__ Wo, const float* __restrict__ bo,
    const float* __restrict__ x, float* __restrict__ out)
{
    __shared__ float ag[16][H];
    const int t  = threadIdx.x;
    const int n0 = blockIdx.x * 16;
    #pragma unroll
    for (int i = 0; i < 16; ++i) ag[i][t] = aggm[(size_t)(n0 + i) * H + t];
    __syncthreads();

    float acc[16];
    #pragma unroll
    for (int i = 0; i < 16; ++i) acc[i] = 0.f;
    const float* wor = Wo + (size_t)t * H;
    for (int kk = 0; kk < H; kk += 4) {
        const float4 w4 = *(const float4*)(wor + kk);
        #pragma unroll
        for (int i = 0; i < 16; ++i) {
            const float4 a4 = *(const float4*)&ag[i][kk];
            acc[i] += w4.x * a4.x + w4.y * a4.y + w4.z * a4.z + w4.w * a4.w;
        }
    }
    const float bov = bo[t];
    #pragma unroll
    for (int i = 0; i < 16; ++i)
        out[(size_t)(n0 + i) * H + t] = x[(size_t)(n0 + i) * H + t] + acc[i] + bov;
}

extern "C" void kernel_launch(void* const* d_in, const int* in_sizes, int n_in,
                              void* d_out, int out_size, void* d_ws, size_t ws_size,
                              hipStream_t stream) {
    const float* x   = (const float*)d_in[0];
    const int*   ei  = (const int*)d_in[1];
    const float* ew  = (const float*)d_in[2];
    const float* ea  = (const float*)d_in[3];
    const float* g   = (const float*)d_in[4];
    const float* b   = (const float*)d_in[5];
    const float* Wq  = (const float*)d_in[6];  const float* bq  = (const float*)d_in[7];
    const float* Wk  = (const float*)d_in[8];  const float* bk  = (const float*)d_in[9];
    const float* Wv  = (const float*)d_in[10]; const float* bv  = (const float*)d_in[11];
    const float* Wo  = (const float*)d_in[12]; const float* bo  = (const float*)d_in[13];
    const float* Wdk = (const float*)d_in[14]; const float* bdk = (const float*)d_in[15];
    const float* Wdv = (const float*)d_in[16]; const float* bdv = (const float*)d_in[17];

    float* q    = (float*)d_ws;
    float* k    = q + (size_t)NN * H;
    float* v    = k + (size_t)NN * H;
    int*   hist = (int*)(v + (size_t)NN * H);
    int*   off  = hist + NN;
    int*   cur  = off + NN + 1;
    int*   perm = cur + NN;
    float* agg  = (float*)(perm + EE);

    hipMemsetAsync(hist, 0, NN * sizeof(int), stream);
    k_hist<<<EE / 256, 256, 0, stream>>>(ei, hist);
    k_ln_qkv<<<NN / 16, 256, 0, stream>>>(x, g, b, Wq, bq, Wk, bk, Wv, bv, q, k, v);
    k_scan<<<1, 1024, 0, stream>>>(hist, off, cur);
    k_scatter<<<EE / 256, 256, 0, stream>>>(ei, cur, perm);
    k_edge_seg<<<NN / 16, 256, 0, stream>>>(q, k, v, ei, ew, ea, Wdk, bdk, Wdv, bdv, off, perm, agg);
    k_out<<<NN / 16, 256, 0, stream>>>(agg, Wo, bo, x, (float*)d_out);
}

// Round 3
// 911.216 us; speedup vs baseline: 2.6807x; 2.6807x over previous
//
#include <hip/hip_runtime.h>
#include <math.h>

#define NN 20000
#define H 256
#define R 64
#define EE 320000
#define LN_EPS 1e-5f

__device__ __forceinline__ float silu_f(float x) { return x / (1.0f + __expf(-x)); }

// ---------------------------------------------------------------------------
// K1: fused LayerNorm + Q/K/V projections.  16 nodes per 256-thread block.
// ---------------------------------------------------------------------------
__global__ __launch_bounds__(256) void k_ln_qkv(
    const float* __restrict__ x, const float* __restrict__ g, const float* __restrict__ b,
    const float* __restrict__ Wq, const float* __restrict__ bq,
    const float* __restrict__ Wk, const float* __restrict__ bk,
    const float* __restrict__ Wv, const float* __restrict__ bv,
    float* __restrict__ q, float* __restrict__ k, float* __restrict__ v)
{
    __shared__ float xn[16][H];          // 16 KB
    const int t  = threadIdx.x;
    const int n0 = blockIdx.x * 16;

    #pragma unroll
    for (int i = 0; i < 16; ++i) xn[i][t] = x[(size_t)(n0 + i) * H + t];
    __syncthreads();

    const int n = t >> 4, s = t & 15;
    float sum = 0.f, sq = 0.f;
    #pragma unroll
    for (int j = 0; j < 16; ++j) { float val = xn[n][s + 16 * j]; sum += val; sq += val * val; }
    #pragma unroll
    for (int off = 8; off; off >>= 1) { sum += __shfl_xor(sum, off); sq += __shfl_xor(sq, off); }
    const float mu  = sum * (1.0f / H);
    const float var = sq * (1.0f / H) - mu * mu;
    const float rs  = rsqrtf(var + LN_EPS);
    #pragma unroll
    for (int j = 0; j < 16; ++j) {
        int c = s + 16 * j;
        float val = xn[n][c];
        xn[n][c] = (val - mu) * rs * g[c] + b[c];
    }
    __syncthreads();

    float aq[16], ak[16], av[16];
    #pragma unroll
    for (int i = 0; i < 16; ++i) { aq[i] = 0.f; ak[i] = 0.f; av[i] = 0.f; }
    const float* wqr = Wq + (size_t)t * H;
    const float* wkr = Wk + (size_t)t * H;
    const float* wvr = Wv + (size_t)t * H;
    for (int kk = 0; kk < H; kk += 4) {
        const float4 wq4 = *(const float4*)(wqr + kk);
        const float4 wk4 = *(const float4*)(wkr + kk);
        const float4 wv4 = *(const float4*)(wvr + kk);
        #pragma unroll
        for (int i = 0; i < 16; ++i) {
            const float4 x4 = *(const float4*)&xn[i][kk];
            aq[i] += wq4.x * x4.x + wq4.y * x4.y + wq4.z * x4.z + wq4.w * x4.w;
            ak[i] += wk4.x * x4.x + wk4.y * x4.y + wk4.z * x4.z + wk4.w * x4.w;
            av[i] += wv4.x * x4.x + wv4.y * x4.y + wv4.z * x4.z + wv4.w * x4.w;
        }
    }
    const float bqv = bq[t], bkv = bk[t], bvv = bv[t];
    #pragma unroll
    for (int i = 0; i < 16; ++i) {
        q[(size_t)(n0 + i) * H + t] = aq[i] + bqv;
        k[(size_t)(n0 + i) * H + t] = ak[i] + bkv;
        v[(size_t)(n0 + i) * H + t] = av[i] + bvv;
    }
}

// ---------------------------------------------------------------------------
// Counting sort of edges by dst: hist -> scan -> scatter(perm)
// ---------------------------------------------------------------------------
__global__ __launch_bounds__(256) void k_hist(const int* __restrict__ ei, int* __restrict__ hist) {
    int e = blockIdx.x * 256 + threadIdx.x;
    if (e < EE) atomicAdd(&hist[ei[EE + e]], 1);
}

__global__ __launch_bounds__(1024) void k_scan(const int* __restrict__ hist,
                                               int* __restrict__ cursor) {
    __shared__ int buf[1024];
    __shared__ int carry_s;
    const int t = threadIdx.x;
    if (t == 0) carry_s = 0;
    __syncthreads();
    for (int base = 0; base < NN; base += 1024) {
        int vv = (base + t < NN) ? hist[base + t] : 0;
        buf[t] = vv;
        __syncthreads();
        #pragma unroll
        for (int ofs = 1; ofs < 1024; ofs <<= 1) {
            int add = (t >= ofs) ? buf[t - ofs] : 0;
            __syncthreads();
            buf[t] += add;
            __syncthreads();
        }
        int excl = buf[t] - vv;
        int carry = carry_s;
        if (base + t < NN) cursor[base + t] = carry + excl;
        __syncthreads();
        if (t == 1023) carry_s = carry + buf[1023];
        __syncthreads();
    }
}

__global__ __launch_bounds__(256) void k_scatter(const int* __restrict__ ei,
                                                 int* __restrict__ cursor, int* __restrict__ perm) {
    int e = blockIdx.x * 256 + threadIdx.x;
    if (e < EE) {
        int d = ei[EE + e];
        int pos = atomicAdd(&cursor[d], 1);
        perm[pos] = e;
    }
}

// ---------------------------------------------------------------------------
// K2: sorted-edge kernel. Block b owns sorted edges [64b, 64b+64).
// Round-1 skeleton (proven 84-VGPR profile): 2 h-halves, w_s[64][128],
// per-thread tile 8 edges x 4 cols. Scatter = register run-flush:
// edges sorted by dst => accumulate equal-dst runs in registers, one
// global atomicAdd per run boundary (~15M atomics vs 82M).
// ---------------------------------------------------------------------------
__global__ __launch_bounds__(256) void k_edge(
    const float* __restrict__ q, const float* __restrict__ k, const float* __restrict__ v,
    const int* __restrict__ ei, const float* __restrict__ ew, const float* __restrict__ ea,
    const float* __restrict__ Wdk, const float* __restrict__ bdk,
    const float* __restrict__ Wdv, const float* __restrict__ bdv,
    const int* __restrict__ perm,
    float* __restrict__ agg)
{
    __shared__ float ea_s[64][R];     // 16 KB
    __shared__ float w_s[R][128];     // 32 KB (one h-half, transposed)
    __shared__ float attn_s[64];
    __shared__ int   pe_s[64], src_s[64], dst_s[64];
    __shared__ float cut_s[64];

    const int t  = threadIdx.x;
    const int eb = blockIdx.x * 64;

    if (t < 64) {
        int e = perm[eb + t];
        pe_s[t]  = e;
        src_s[t] = ei[e];
        dst_s[t] = ei[EE + e];
        float r  = ew[e];
        cut_s[t] = (r < 5.0f) ? 0.5f * (__cosf(r * 0.6283185307f) + 1.0f) : 0.0f;
        attn_s[t] = 0.f;
    }
    __syncthreads();
    {   // stage ea rows via perm: 4 threads per row, 4 float4 each
        const int row = t >> 2, c0 = (t & 3) * 16;
        const float* sp = ea + (size_t)pe_s[row] * R + c0;
        #pragma unroll
        for (int j = 0; j < 4; ++j)
            *(float4*)&ea_s[row][c0 + 4 * j] = *(const float4*)(sp + 4 * j);
    }

    const int tx = t & 31, ty = t >> 5;
    const int h0 = tx * 4, e0 = ty * 8;

    // ---------------- pass A: attention logits ----------------
    for (int hh = 0; hh < 2; ++hh) {
        __syncthreads();   // ea/meta ready (iter0); prior w_s readers done (iter1)
        {   // w_s[r][hl] = Wdk[(hh*128+hl)*R + r]
            const int hl = t & 127, r0 = (t >> 7) * 32;
            const float* sp = Wdk + (size_t)(hh * 128 + hl) * R + r0;
            #pragma unroll
            for (int j = 0; j < 32; ++j) w_s[r0 + j][hl] = sp[j];
        }
        __syncthreads();

        float acc[8][4];
        const float4 bi = *(const float4*)(bdk + hh * 128 + h0);
        #pragma unroll
        for (int i = 0; i < 8; ++i) { acc[i][0] = bi.x; acc[i][1] = bi.y; acc[i][2] = bi.z; acc[i][3] = bi.w; }

        for (int r4 = 0; r4 < R; r4 += 4) {
            const float4 w0 = *(const float4*)&w_s[r4 + 0][h0];
            const float4 w1 = *(const float4*)&w_s[r4 + 1][h0];
            const float4 w2 = *(const float4*)&w_s[r4 + 2][h0];
            const float4 w3 = *(const float4*)&w_s[r4 + 3][h0];
            #pragma unroll
            for (int i = 0; i < 8; ++i) {
                const float4 a = *(const float4*)&ea_s[e0 + i][r4];
                acc[i][0] += a.x * w0.x + a.y * w1.x + a.z * w2.x + a.w * w3.x;
                acc[i][1] += a.x * w0.y + a.y * w1.y + a.z * w2.y + a.w * w3.y;
                acc[i][2] += a.x * w0.z + a.y * w1.z + a.z * w2.z + a.w * w3.z;
                acc[i][3] += a.x * w0.w + a.y * w1.w + a.z * w2.w + a.w * w3.w;
            }
        }
        #pragma unroll
        for (int i = 0; i < 8; ++i) {
            const int d = dst_s[e0 + i], s = src_s[e0 + i];
            const float4 qi = *(const float4*)(q + (size_t)d * H + hh * 128 + h0);
            const float4 kj = *(const float4*)(k + (size_t)s * H + hh * 128 + h0);
            float part = qi.x * kj.x * silu_f(acc[i][0]) + qi.y * kj.y * silu_f(acc[i][1])
                       + qi.z * kj.z * silu_f(acc[i][2]) + qi.w * kj.w * silu_f(acc[i][3]);
            #pragma unroll
            for (int off = 16; off; off >>= 1) part += __shfl_xor(part, off);
            if (tx == 0) attn_s[e0 + i] += part;   // same thread both halves: no race
        }
    }
    __syncthreads();
    if (t < 64) attn_s[t] = silu_f(attn_s[t]) * cut_s[t];

    // ---------------- pass B: messages + run-flush scatter ----------------
    for (int hh = 0; hh < 2; ++hh) {
        __syncthreads();   // attn finalized (iter0); prior w_s readers done (iter1)
        {
            const int hl = t & 127, r0 = (t >> 7) * 32;
            const float* sp = Wdv + (size_t)(hh * 128 + hl) * R + r0;
            #pragma unroll
            for (int j = 0; j < 32; ++j) w_s[r0 + j][hl] = sp[j];
        }
        __syncthreads();

        float acc[8][4];
        const float4 bi = *(const float4*)(bdv + hh * 128 + h0);
        #pragma unroll
        for (int i = 0; i < 8; ++i) { acc[i][0] = bi.x; acc[i][1] = bi.y; acc[i][2] = bi.z; acc[i][3] = bi.w; }

        for (int r4 = 0; r4 < R; r4 += 4) {
            const float4 w0 = *(const float4*)&w_s[r4 + 0][h0];
            const float4 w1 = *(const float4*)&w_s[r4 + 1][h0];
            const float4 w2 = *(const float4*)&w_s[r4 + 2][h0];
            const float4 w3 = *(const float4*)&w_s[r4 + 3][h0];
            #pragma unroll
            for (int i = 0; i < 8; ++i) {
                const float4 a = *(const float4*)&ea_s[e0 + i][r4];
                acc[i][0] += a.x * w0.x + a.y * w1.x + a.z * w2.x + a.w * w3.x;
                acc[i][1] += a.x * w0.y + a.y * w1.y + a.z * w2.y + a.w * w3.y;
                acc[i][2] += a.x * w0.z + a.y * w1.z + a.z * w2.z + a.w * w3.z;
                acc[i][3] += a.x * w0.w + a.y * w1.w + a.z * w2.w + a.w * w3.w;
            }
        }

        // register run-flush: dst_s is sorted within the block
        float4 m = {0.f, 0.f, 0.f, 0.f};
        int cur_d = -1;
        #pragma unroll
        for (int i = 0; i < 8; ++i) {
            const int d = dst_s[e0 + i], s = src_s[e0 + i];
            const float a = attn_s[e0 + i];
            const float4 vj = *(const float4*)(v + (size_t)s * H + hh * 128 + h0);
            float4 mi;
            mi.x = vj.x * silu_f(acc[i][0]) * a;
            mi.y = vj.y * silu_f(acc[i][1]) * a;
            mi.z = vj.z * silu_f(acc[i][2]) * a;
            mi.w = vj.w * silu_f(acc[i][3]) * a;
            if (d != cur_d) {
                if (cur_d >= 0) {
                    float* dp = agg + (size_t)cur_d * H + hh * 128 + h0;
                    atomicAdd(dp + 0, m.x); atomicAdd(dp + 1, m.y);
                    atomicAdd(dp + 2, m.z); atomicAdd(dp + 3, m.w);
                }
                m = mi; cur_d = d;
            } else {
                m.x += mi.x; m.y += mi.y; m.z += mi.z; m.w += mi.w;
            }
        }
        {
            float* dp = agg + (size_t)cur_d * H + hh * 128 + h0;
            atomicAdd(dp + 0, m.x); atomicAdd(dp + 1, m.y);
            atomicAdd(dp + 2, m.z); atomicAdd(dp + 3, m.w);
        }
    }
}

// ---------------------------------------------------------------------------
// K3: out = x + agg @ Wo^T + bo.
// ---------------------------------------------------------------------------
__global__ __launch_bounds__(256) void k_out(
    const float* __restrict__ aggm, const float* __restrict__ Wo, const float* __restrict__ bo,
    const float* __restrict__ x, float* __restrict__ out)
{
    __shared__ float ag[16][H];
    const int t  = threadIdx.x;
    const int n0 = blockIdx.x * 16;
    #pragma unroll
    for (int i = 0; i < 16; ++i) ag[i][t] = aggm[(size_t)(n0 + i) * H + t];
    __syncthreads();

    float acc[16];
    #pragma unroll
    for (int i = 0; i < 16; ++i) acc[i] = 0.f;
    const float* wor = Wo + (size_t)t * H;
    for (int kk = 0; kk < H; kk += 4) {
        const float4 w4 = *(const float4*)(wor + kk);
        #pragma unroll
        for (int i = 0; i < 16; ++i) {
            const float4 a4 = *(const float4*)&ag[i][kk];
            acc[i] += w4.x * a4.x + w4.y * a4.y + w4.z * a4.z + w4.w * a4.w;
        }
    }
    const float bov = bo[t];
    #pragma unroll
    for (int i = 0; i < 16; ++i)
        out[(size_t)(n0 + i) * H + t] = x[(size_t)(n0 + i) * H + t] + acc[i] + bov;
}

extern "C" void kernel_launch(void* const* d_in, const int* in_sizes, int n_in,
                              void* d_out, int out_size, void* d_ws, size_t ws_size,
                              hipStream_t stream) {
    const float* x   = (const float*)d_in[0];
    const int*   ei  = (const int*)d_in[1];
    const float* ew  = (const float*)d_in[2];
    const float* ea  = (const float*)d_in[3];
    const float* g   = (const float*)d_in[4];
    const float* b   = (const float*)d_in[5];
    const float* Wq  = (const float*)d_in[6];  const float* bq  = (const float*)d_in[7];
    const float* Wk  = (const float*)d_in[8];  const float* bk  = (const float*)d_in[9];
    const float* Wv  = (const float*)d_in[10]; const float* bv  = (const float*)d_in[11];
    const float* Wo  = (const float*)d_in[12]; const float* bo  = (const float*)d_in[13];
    const float* Wdk = (const float*)d_in[14]; const float* bdk = (const float*)d_in[15];
    const float* Wdv = (const float*)d_in[16]; const float* bdv = (const float*)d_in[17];

    float* q    = (float*)d_ws;
    float* k    = q + (size_t)NN * H;
    float* v    = k + (size_t)NN * H;
    int*   hist = (int*)(v + (size_t)NN * H);
    int*   cur  = hist + NN;
    int*   perm = cur + NN;
    float* agg  = (float*)(perm + EE);

    hipMemsetAsync(hist, 0, NN * sizeof(int), stream);
    hipMemsetAsync(agg, 0, (size_t)NN * H * sizeof(float), stream);
    k_hist<<<EE / 256, 256, 0, stream>>>(ei, hist);
    k_ln_qkv<<<NN / 16, 256, 0, stream>>>(x, g, b, Wq, bq, Wk, bk, Wv, bv, q, k, v);
    k_scan<<<1, 1024, 0, stream>>>(hist, cur);
    k_scatter<<<EE / 256, 256, 0, stream>>>(ei, cur, perm);
    k_edge<<<EE / 64, 256, 0, stream>>>(q, k, v, ei, ew, ea, Wdk, bdk, Wdv, bdv, perm, agg);
    k_out<<<NN / 16, 256, 0, stream>>>(agg, Wo, bo, x, (float*)d_out);
}